// Round 8
// baseline (234.018 us; speedup 1.0000x reference)
//
#include <hip/hip_runtime.h>

// Median filter (k=22, REFLECT) + blend, NHWC (2,224,224,3) fp32.
// One wave per 8 consecutive-x pixels, processed as 2 QUADS. Window (484) in
// 8 regs/lane per pixel, ballot counting. Serial-chain killer: a 5-point
// PARALLEL threshold ladder probes all 4 pixels of a quad at once (160
// independent cmp+ballot = one latency round) centered on the warm start;
// one interp probe; then R6's proven pair adaptive loop (sticky, usually 0
// iters) + sign-folded pair peel -> exact for any input incl. REFLECT
// duplicates. All cross-lane via __shfl_xor/__ballot; no uninitialized reads.

#define HH 224
#define WW 224
#define CHN 3
#define KK 22
#define PT 10            // pad top/left; bottom/right = 11
#define AREA (KK * KK)   // 484
#define RANK 242         // median = 242nd smallest (1-indexed)
#define PXW 8
#define XGS (WW / PXW)   // 28
#define DT 2             // peel when |count-RANK| <= DT

#define INFF  __int_as_float(0x7f800000)
#define NINFF __int_as_float(0xff800000)

__device__ __forceinline__ int reflect224(int g) {
    int a = abs(g);
    return min(a, 2 * (HH - 1) - a);
}

__device__ __forceinline__ int count8(const float v[8], float t) {
    int c = 0;
#pragma unroll
    for (int i = 0; i < 8; ++i)
        c += __popcll(__ballot(v[i] < t));
    return c;
}

__device__ __forceinline__ void gather(float v[8], const float* __restrict__ img,
                                       const int voff[8], int lane, int x) {
    if (x >= PT && x <= WW - 1 - (KK - 1 - PT)) {      // interior: x in [10,212]
        const float* base = img + (x - PT) * CHN;      // wave-uniform base
#pragma unroll
        for (int i = 0; i < 8; ++i) v[i] = base[voff[i]];
    } else {
#pragma unroll
        for (int i = 0; i < 8; ++i) {
            int s   = i * 64 + lane;
            int se  = min(s, AREA - 1);
            int row = se / KK;
            int col = se - row * KK;
            int gy672 = voff[i] - col * CHN;
            int gx = reflect224(x - PT + col);
            v[i] = img[gy672 + gx * CHN];
        }
    }
    v[7] = (lane < AREA - 448) ? v[7] : INFF;          // slots >= 484 -> +INF
}

__global__ __launch_bounds__(256)
void median_blend_kernel(const float* __restrict__ in,
                         const float* __restrict__ blend,
                         float* __restrict__ out) {
    const int lane = threadIdx.x & 63;
    const int wid  = threadIdx.x >> 6;
    const int wg = blockIdx.x * 4 + wid;        // wave-uniform group id
    // wg = ((b*CHN + c)*HH + y)*XGS + xg
    const int xg = wg % XGS;
    const int t1 = wg / XGS;
    const int y  = t1 % HH;
    const int t2 = t1 / HH;
    const int c  = t2 % CHN;
    const int b  = t2 / CHN;

    const float f = blend[0];
    const float* img  = in  + (size_t)b * (HH * WW * CHN) + c;
    float*       outp = out + (size_t)b * (HH * WW * CHN) + c;

    // per-wave lane constants: voff = gy*672 + col*3 (vertical reflect baked in)
    int voff[8];
#pragma unroll
    for (int i = 0; i < 8; ++i) {
        int s   = i * 64 + lane;
        int se  = min(s, AREA - 1);
        int row = se / KK;
        int col = se - row * KK;
        int gy  = reflect224(y - PT + row);
        voff[i] = gy * (WW * CHN) + col * CHN;
    }

    const int x0 = xg * PXW;
    float tprev = 0.5f;

#pragma unroll 1
    for (int q = 0; q < 2; ++q) {
        const int xq = x0 + q * 4;

        // ---- quad gather ----
        float v[4][8];
#pragma unroll
        for (int p = 0; p < 4; ++p)
            gather(v[p], img, voff, lane, xq + p);

        // ---- 5-point parallel ladder (one latency round, 160 cmps) ----
        const float dl = (q == 0) ? 0.020f : 0.012f;
        const float tc = tprev;
        int Cl[4][5];
#pragma unroll
        for (int p = 0; p < 4; ++p)
#pragma unroll
            for (int k = 0; k < 5; ++k)
                Cl[p][k] = count8(v[p], tc + (float)(k - 2) * dl);

        // ---- per-pixel bracket from ladder + one interp probe ----
        float t[4], lo[4], hi[4];
        int C[4], clo[4], chi[4];
#pragma unroll
        for (int p = 0; p < 4; ++p) {
            float l = 0.0f, h = 1.0f;
            int cl = 0, ch = AREA;
#pragma unroll
            for (int k = 0; k < 5; ++k) {       // largest tk with C < RANK
                float tk = tc + (float)(k - 2) * dl;
                if (Cl[p][k] < RANK && tk > l) { l = tk; cl = Cl[p][k]; }
            }
#pragma unroll
            for (int k = 0; k < 5; ++k) {       // smallest tk with C >= RANK
                float tk = tc + (float)(k - 2) * dl;
                if (Cl[p][k] >= RANK && tk < h) { h = tk; ch = Cl[p][k]; }
            }
            float tn = l + (h - l) * (float)(RANK - cl) *
                       __builtin_amdgcn_rcpf((float)(ch - cl));
            if (!(tn > l && tn < h)) tn = 0.5f * (l + h);
            if (!(tn > l && tn < h)) tn = l;    // degenerate: recount at l
            t[p] = tn; lo[p] = l; hi[p] = h; clo[p] = cl; chi[p] = ch;
        }
#pragma unroll
        for (int p = 0; p < 4; ++p)
            C[p] = count8(v[p], t[p]);

        float med[4];

        // ---- two pairs: adaptive (sticky, usually 0 iters) + folded peel ----
#pragma unroll
        for (int pr = 0; pr < 2; ++pr) {
            const int A = 2 * pr, B = 2 * pr + 1;

            float tA = t[A], tB = t[B];
            int   CA = C[A], CB = C[B];
            float loA = lo[A], hiA = hi[A], loB = lo[B], hiB = hi[B];
            int   cloA = clo[A], chiA = chi[A], cloB = clo[B], chiB = chi[B];
            bool actA = true, actB = true;
#pragma unroll 1
            for (int it = 0; it < 8 && (actA || actB); ++it) {
                if (actA) {
                    int d = CA - RANK;
                    if (d >= -DT && d <= DT) actA = false;
                    else {
                        if (d > 0) { hiA = tA; chiA = CA; }
                        else       { loA = tA; cloA = CA; }
                        float tn = loA + (hiA - loA) * (float)(RANK - cloA) *
                                   __builtin_amdgcn_rcpf((float)(chiA - cloA));
                        if (!(tn > loA && tn < hiA)) {
                            tn = 0.5f * (loA + hiA);
                            if (!(tn > loA && tn < hiA)) actA = false;
                        }
                        if (actA) { tA = tn; CA = count8(v[A], tA); }
                    }
                }
                if (actB) {
                    int d = CB - RANK;
                    if (d >= -DT && d <= DT) actB = false;
                    else {
                        if (d > 0) { hiB = tB; chiB = CB; }
                        else       { loB = tB; cloB = CB; }
                        float tn = loB + (hiB - loB) * (float)(RANK - cloB) *
                                   __builtin_amdgcn_rcpf((float)(chiB - cloB));
                        if (!(tn > loB && tn < hiB)) {
                            tn = 0.5f * (loB + hiB);
                            if (!(tn > loB && tn < hiB)) actB = false;
                        }
                        if (actB) { tB = tn; CB = count8(v[B], tB); }
                    }
                }
            }

            // sign-folded pair peel (exact; R6-proven)
            const int dA = CA - RANK, dB = CB - RANK;
            const bool topA = (dA >= 0), topB = (dB >= 0);
            int eA = topA ? dA + 1 : -dA;
            int eB = topB ? dB + 1 : -dB;
            const int sgnA = topA ? 0 : 0x80000000;
            const int sgnB = topB ? 0 : 0x80000000;
#pragma unroll
            for (int i = 0; i < 8; ++i) {
                bool ltA = v[A][i] < tA;           // member iff lt == top
                float sA = __int_as_float(__float_as_int(v[A][i]) ^ sgnA);
                v[A][i] = (ltA == topA) ? sA : NINFF;
                bool ltB = v[B][i] < tB;
                float sB = __int_as_float(__float_as_int(v[B][i]) ^ sgnB);
                v[B][i] = (ltB == topB) ? sB : NINFF;
            }

            float medA = tA, medB = tB;            // provably overwritten
            bool doneA = false, doneB = false;
#pragma unroll 1
            for (int r = 0; r < 300 && !(doneA && doneB); ++r) {
                float mA = fmaxf(fmaxf(fmaxf(v[A][0], v[A][1]), fmaxf(v[A][2], v[A][3])),
                                 fmaxf(fmaxf(v[A][4], v[A][5]), fmaxf(v[A][6], v[A][7])));
                float mB = fmaxf(fmaxf(fmaxf(v[B][0], v[B][1]), fmaxf(v[B][2], v[B][3])),
                                 fmaxf(fmaxf(v[B][4], v[B][5]), fmaxf(v[B][6], v[B][7])));
#pragma unroll
                for (int off = 32; off > 0; off >>= 1) {
                    mA = fmaxf(mA, __shfl_xor(mA, off, 64));
                    mB = fmaxf(mB, __shfl_xor(mB, off, 64));
                }
                if (!doneA) {
                    int qq = 0;
#pragma unroll
                    for (int i = 0; i < 8; ++i)
                        qq += __popcll(__ballot(v[A][i] == mA));
                    if (eA <= qq) {
                        medA = __int_as_float(__float_as_int(mA) ^ sgnA);
                        doneA = true;
                    } else {
                        eA -= qq;
#pragma unroll
                        for (int i = 0; i < 8; ++i)
                            v[A][i] = (v[A][i] == mA) ? NINFF : v[A][i];
                    }
                }
                if (!doneB) {
                    int qq = 0;
#pragma unroll
                    for (int i = 0; i < 8; ++i)
                        qq += __popcll(__ballot(v[B][i] == mB));
                    if (eB <= qq) {
                        medB = __int_as_float(__float_as_int(mB) ^ sgnB);
                        doneB = true;
                    } else {
                        eB -= qq;
#pragma unroll
                        for (int i = 0; i < 8; ++i)
                            v[B][i] = (v[B][i] == mB) ? NINFF : v[B][i];
                    }
                }
            }
            med[A] = medA;
            med[B] = medB;
        }
        tprev = med[3];                            // warm start for next quad

        // ---- blend + store (4 px) ----
#pragma unroll
        for (int p = 0; p < 4; ++p) {
            const int x = xq + p;
            const float xc = img[y * (WW * CHN) + x * CHN];
            if (lane == 0)
                outp[y * (WW * CHN) + x * CHN] = med[p] + f * (xc - med[p]);
        }
    }
}

extern "C" void kernel_launch(void* const* d_in, const int* in_sizes, int n_in,
                              void* d_out, int out_size, void* d_ws, size_t ws_size,
                              hipStream_t stream) {
    const float* in    = (const float*)d_in[0];
    const float* blend = (const float*)d_in[1];
    float* out = (float*)d_out;

    const int nwaves  = 2 * CHN * HH * XGS;   // 37632
    const int nblocks = nwaves / 4;           // 9408
    median_blend_kernel<<<nblocks, 256, 0, stream>>>(in, blend, out);
}